// Round 1
// baseline (14756.888 us; speedup 1.0000x reference)
//
#include <hip/hip_runtime.h>
#include <stdint.h>

#define NB 256
#define PERIOD 30

__device__ __forceinline__ float frcp(float x){ return __builtin_amdgcn_rcpf(x); }

// tanh(x) = 1 - 2/(exp(2x)+1); exp via native v_exp, rcp via v_rcp (1-ulp each)
__device__ __forceinline__ float fast_tanh(float x){
  float e = __expf(2.0f*x);
  return fmaf(-2.0f, frcp(e + 1.0f), 1.0f);
}

// Threefry-2x32, 20 rounds, key = (0, 42)  [jax.random.key(42)]
__device__ __forceinline__ void threefry2x32_k42(uint32_t x0, uint32_t x1,
                                                 uint32_t& o0, uint32_t& o1){
  const uint32_t ks0 = 0u;
  const uint32_t ks1 = 42u;
  const uint32_t ks2 = 0u ^ 42u ^ 0x1BD11BDAu;
  x0 += ks0; x1 += ks1;
#define TFR(rot) { x0 += x1; x1 = (x1 << (rot)) | (x1 >> (32 - (rot))); x1 ^= x0; }
  TFR(13) TFR(15) TFR(26) TFR(6)
  x0 += ks1; x1 += ks2 + 1u;
  TFR(17) TFR(29) TFR(16) TFR(24)
  x0 += ks2; x1 += ks0 + 2u;
  TFR(13) TFR(15) TFR(26) TFR(6)
  x0 += ks0; x1 += ks1 + 3u;
  TFR(17) TFR(29) TFR(16) TFR(24)
  x0 += ks1; x1 += ks2 + 4u;
  TFR(13) TFR(15) TFR(26) TFR(6)
  x0 += ks2; x1 += ks0 + 5u;
#undef TFR
  o0 = x0; o1 = x1;
}

// Mirror jax.random.normal f32: u = max(lo, u01*2 + lo), lo = nextafter(-1,0);
// then sqrt(2) * erfinv(u) with XLA's exact f32 polynomial (Giles).
__device__ __forceinline__ float normal_from_bits(uint32_t bits){
  float f = __uint_as_float((bits >> 9) | 0x3f800000u) - 1.0f;   // [0,1)
  const float lo = -0.99999994f;
  float u = fmaf(f, 2.0f, lo);
  u = fmaxf(u, lo);
  float w = -log1pf(-u*u);
  float p;
  if (w < 5.0f){
    float ww = w - 2.5f;
    p = 2.81022636e-08f;
    p = fmaf(p, ww, 3.43273939e-07f);
    p = fmaf(p, ww, -3.5233877e-06f);
    p = fmaf(p, ww, -4.39150654e-06f);
    p = fmaf(p, ww, 0.00021858087f);
    p = fmaf(p, ww, -0.00125372503f);
    p = fmaf(p, ww, -0.00417768164f);
    p = fmaf(p, ww, 0.246640727f);
    p = fmaf(p, ww, 1.50140941f);
  } else {
    float ww = sqrtf(w) - 3.0f;
    p = -0.000200214257f;
    p = fmaf(p, ww, 0.000100950558f);
    p = fmaf(p, ww, 0.00134934322f);
    p = fmaf(p, ww, -0.00367342844f);
    p = fmaf(p, ww, 0.00573950773f);
    p = fmaf(p, ww, -0.0076224613f);
    p = fmaf(p, ww, 0.00943887047f);
    p = fmaf(p, ww, 1.00167406f);
    p = fmaf(p, ww, 2.83297682f);
  }
  return 1.41421356f * (p * u);
}

// Network + analytic JVPs w.r.t. (y2, y3).
// s_k1 = SIGMA * sum_i (1-t_i^2)*A2_i*Wo_i  where A2_i = sum_j (1-h_j^2)*W0[0,j]*Wh[j,i]
__device__ __forceinline__ void net_eval(float y2, float y3,
  const float* __restrict__ W0,  const float* __restrict__ b0,
  const float* __restrict__ Wh1, const float* __restrict__ bh1,
  const float* __restrict__ Wo1, const float* __restrict__ bo1,
  const float* __restrict__ Wh2, const float* __restrict__ bh2,
  const float* __restrict__ Wo2, const float* __restrict__ bo2,
  const float* __restrict__ Wh3, const float* __restrict__ bh3,
  const float* __restrict__ Wo3, const float* __restrict__ bo3,
  float& q1, float& q2, float& q3,
  float& s11, float& s21, float& s31,
  float& s12, float& s22, float& s32)
{
  float q[3], sA[3], sB[3];
#pragma unroll
  for (int k = 0; k < 3; ++k){
    const float* Wh = (k==0) ? Wh1 : ((k==1) ? Wh2 : Wh3);
    const float* bh = (k==0) ? bh1 : ((k==1) ? bh2 : bh3);
    const float* Wo = (k==0) ? Wo1 : ((k==1) ? Wo2 : Wo3);
    const float* bo = (k==0) ? bo1 : ((k==1) ? bo2 : bo3);

    float at[32], a2[32], a3[32];
#pragma unroll
    for (int i = 0; i < 32; ++i){ at[i] = bh[i]; a2[i] = 0.0f; a3[i] = 0.0f; }

    for (int j = 0; j < 64; ++j){                 // rolled: uniform scalar loads
      float w0a = W0[j];
      float w0b = W0[64 + j];
      float pre = fmaf(y2, w0a, fmaf(y3, w0b, b0[j]));
      float h  = fast_tanh(pre);
      float u  = fmaf(-h, h, 1.0f);               // 1 - h^2
      float gA = u * w0a;
      float gB = u * w0b;
      const float* wr = Wh + j * 32;
#pragma unroll
      for (int i = 0; i < 32; ++i){
        float w = wr[i];
        at[i] = fmaf(h,  w, at[i]);
        a2[i] = fmaf(gA, w, a2[i]);
        a3[i] = fmaf(gB, w, a3[i]);
      }
    }

    float accq = 0.0f, accA = 0.0f, accB = 0.0f;
#pragma unroll
    for (int i = 0; i < 32; ++i){
      float t  = fast_tanh(at[i]);
      float dt = fmaf(-t, t, 1.0f);               // 1 - t^2
      float wo = Wo[i];
      accq = fmaf(t, wo, accq);
      accA = fmaf(dt * a2[i], wo, accA);
      accB = fmaf(dt * a3[i], wo, accB);
    }
    float qq = __expf(accq + bo[0]);
    q[k]  = qq;
    sA[k] = 0.03f * accA;                         // SIGMA * dq/dy2 / q
    sB[k] = 0.03f * accB;
  }
  q1 = q[0]; q2 = q[1]; q3 = q[2];
  s11 = sA[0]; s21 = sA[1]; s31 = sA[2];
  s12 = sB[0]; s22 = sB[1]; s32 = sB[2];
}

__global__ __launch_bounds__(NB)
void sim_kernel(const float* __restrict__ Y,
  const float* __restrict__ W0,  const float* __restrict__ b0,
  const float* __restrict__ Wh1, const float* __restrict__ bh1,
  const float* __restrict__ Wo1, const float* __restrict__ bo1,
  const float* __restrict__ Wh2, const float* __restrict__ bh2,
  const float* __restrict__ Wo2, const float* __restrict__ bo2,
  const float* __restrict__ Wh3, const float* __restrict__ bh3,
  const float* __restrict__ Wo3, const float* __restrict__ bo3,
  float* __restrict__ out, int n)
{
  const int gid = blockIdx.x * NB + threadIdx.x;
  const int ii  = (gid < n) ? gid : (n - 1);
  const float valid = (gid < n) ? 1.0f : 0.0f;

  const float2 yv = ((const float2*)Y)[ii];
  const float y2 = yv.x, y3 = yv.y;

  const float GAMMA = 1.2f, DT = 0.005f, SIGMA = 0.03f;
  const float KAPPA = 0.2f, YBAR = 2.0f, RHO = 0.03f, Bc = 1.0f, Cc = 0.1f;

  float q1,q2,q3,s11,s21,s31,s12,s22,s32;
  net_eval(y2, y3, W0,b0,Wh1,bh1,Wo1,bo1,Wh2,bh2,Wo2,bo2,Wh3,bh3,Wo3,bo3,
           q1,q2,q3,s11,s21,s31,s12,s22,s32);
  float Y2 = y2, Y3 = y3;
  float loss = 0.0f;

  for (int t = 0; t < PERIOD; ++t){
    // --- noise: partitionable threefry rollout, counter = flat index (u64) ---
    uint32_t idx0 = 2u * ((uint32_t)t * (uint32_t)n + (uint32_t)ii);
    uint32_t a0, a1, c0, c1;
    threefry2x32_k42(0u, idx0,      a0, a1);
    threefry2x32_k42(0u, idx0 + 1u, c0, c1);
    float dZ1 = 0.070710678f * normal_from_bits(a0 ^ a1);
    float dZ2 = 0.070710678f * normal_from_bits(c0 ^ c1);

    // --- step math (mirror reference, f32) ---
    float Wt  = q1 + q2 + q3;
    float q1h = q1 / Wt;
    float q2h = q2 / Wt;
    float q3h = 1.0f - q1h - q2h;
    float q1sq = q1 * q1;
    float c   = Bc*q1 - Cc*q1sq + Y2 + Y3;
    float bq  = Bc*q1 - 2.0f*Cc*q1sq;
    float sc1 = fmaf(bq, s11, SIGMA);
    float sc2 = fmaf(bq, s12, SIGMA);
    float sW1 = q1*s11 + q2*s21 + q3*s31;
    float sW2 = q1*s12 + q2*s22 + q3*s32;
    float sJ1 = 6.0f * (sc1/c - sW1/Wt);
    float sJ2 = 6.0f * (sc2/c - sW2/Wt);
    float d11 = s11*s11 + s12*s12;
    float d12 = s11*s21 + s12*s22;
    float d13 = s11*s31 + s12*s32;
    float d22 = s21*s21 + s22*s22;
    float d23 = s21*s31 + s22*s32;
    float d33 = s31*s31 + s32*s32;
    const float oneMG = 1.0f - GAMMA;   // -(0.2)
    float p1 = GAMMA*(q1h*d11 + q2h*d12 + q3h*d13) - oneMG*(sJ1*s11 + sJ2*s12);
    float p2 = GAMMA*(q1h*d12 + q2h*d22 + q3h*d23) - oneMG*(sJ1*s21 + sJ2*s22);
    float p3 = GAMMA*(q1h*d13 + q2h*d23 + q3h*d33) - oneMG*(sJ1*s31 + sJ2*s32);
    float muY2 = KAPPA * (YBAR - Y2);
    float muY3 = KAPPA * (YBAR - Y3);
    float r = RHO + GAMMA*(bq*(p1 - (Bc - Cc*q1)) - Cc*q1sq*d11 + muY2 + muY3)/c
                  - 1.32f*(sc1*sc1 + sc2*sc2)/(c*c);
    r = r / (1.0f - GAMMA*bq/c);
    float mu1 = r + p1 - (Bc - Cc*q1);
    float mu2 = r + p2 - Y2/q2;
    float mu3 = r + p3 - Y3/q3;
    float q1n = q1 * (1.0f + mu1*DT + s11*dZ1 + s12*dZ2);
    float q2n = q2 * (1.0f + mu2*DT + s21*dZ1 + s22*dZ2);
    float q3n = q3 * (1.0f + mu3*DT + s31*dZ1 + s32*dZ2);
    float Y2n = Y2 + muY2*DT + SIGMA*dZ1;
    float Y3n = Y3 + muY3*DT + SIGMA*dZ2;

    // --- network at new point (also refreshes s-state) ---
    float qt1, qt2, qt3;
    net_eval(Y2n, Y3n, W0,b0,Wh1,bh1,Wo1,bo1,Wh2,bh2,Wo2,bo2,Wh3,bh3,Wo3,bo3,
             qt1,qt2,qt3, s11,s21,s31,s12,s22,s32);

    float e1 = q1n - qt1, e2 = q2n - qt2, e3 = q3n - qt3;
    loss += e1*e1 + e2*e2 + e3*e3;

    q1 = q1n; q2 = q2n; q3 = q3n; Y2 = Y2n; Y3 = Y3n;
  }

  loss *= valid * (1.0f / ((float)15000000));   // / (n * PERIOD), n = 500000

  // --- block reduction -> one atomic per block ---
#pragma unroll
  for (int off = 32; off > 0; off >>= 1)
    loss += __shfl_down(loss, off, 64);
  __shared__ float sred[NB / 64];
  const int lane = threadIdx.x & 63;
  const int wv   = threadIdx.x >> 6;
  if (lane == 0) sred[wv] = loss;
  __syncthreads();
  if (threadIdx.x == 0){
    float s = 0.0f;
#pragma unroll
    for (int w = 0; w < NB / 64; ++w) s += sred[w];
    atomicAdd(out, s);
  }
}

extern "C" void kernel_launch(void* const* d_in, const int* in_sizes, int n_in,
                              void* d_out, int out_size, void* d_ws, size_t ws_size,
                              hipStream_t stream)
{
  const float* Y   = (const float*)d_in[0];
  const float* W0  = (const float*)d_in[1];
  const float* b0  = (const float*)d_in[2];
  const float* Wh1 = (const float*)d_in[3];
  const float* bh1 = (const float*)d_in[4];
  const float* Wo1 = (const float*)d_in[5];
  const float* bo1 = (const float*)d_in[6];
  const float* Wh2 = (const float*)d_in[7];
  const float* bh2 = (const float*)d_in[8];
  const float* Wo2 = (const float*)d_in[9];
  const float* bo2 = (const float*)d_in[10];
  const float* Wh3 = (const float*)d_in[11];
  const float* bh3 = (const float*)d_in[12];
  const float* Wo3 = (const float*)d_in[13];
  const float* bo3 = (const float*)d_in[14];

  const int n = in_sizes[0] / 2;

  hipMemsetAsync(d_out, 0, sizeof(float), stream);

  const int grid = (n + NB - 1) / NB;
  sim_kernel<<<grid, NB, 0, stream>>>(Y,
      W0, b0, Wh1, bh1, Wo1, bo1, Wh2, bh2, Wo2, bo2, Wh3, bh3, Wo3, bo3,
      (float*)d_out, n);
}